// Round 3
// baseline (11157.543 us; speedup 1.0000x reference)
//
#include <hip/hip_runtime.h>
#include <math.h>
#include <stdint.h>

// Problem constants
#define B 32
#define E 512
#define H 1024
#define V 32000
#define T_MAX 48
// out layout offsets (floats)
#define OUT_LOGP 1536
#define OUT_H    49153536
#define OUT_C    50726400

#define NCHUNK 8
#define CHV    4000

// ---------------- threefry2x32 (exact JAX algorithm) ----------------
__host__ __device__ inline void threefry2x32(unsigned int k0, unsigned int k1,
                                             unsigned int x0, unsigned int x1,
                                             unsigned int& o0, unsigned int& o1) {
  unsigned int ks0 = k0, ks1 = k1, ks2 = k0 ^ k1 ^ 0x1BD11BDAu;
  x0 += ks0; x1 += ks1;
#define TFR(r) { x0 += x1; x1 = (x1 << (r)) | (x1 >> (32 - (r))); x1 ^= x0; }
  TFR(13) TFR(15) TFR(26) TFR(6)   x0 += ks1; x1 += ks2 + 1u;
  TFR(17) TFR(29) TFR(16) TFR(24)  x0 += ks2; x1 += ks0 + 2u;
  TFR(13) TFR(15) TFR(26) TFR(6)   x0 += ks0; x1 += ks1 + 3u;
  TFR(17) TFR(29) TFR(16) TFR(24)  x0 += ks1; x1 += ks2 + 4u;
  TFR(13) TFR(15) TFR(26) TFR(6)   x0 += ks2; x1 += ks0 + 5u;
#undef TFR
  o0 = x0; o1 = x1;
}

// ---------------- K0a: init hT0/cT0 = cond @ W^T + b (transposed [H][B]) ----
__global__ __launch_bounds__(512) void k_init(const float* __restrict__ cond,
                                              const float* __restrict__ Wh, const float* __restrict__ bh,
                                              const float* __restrict__ Wc, const float* __restrict__ bc,
                                              float* __restrict__ hT0, float* __restrict__ cT0) {
  int lane = threadIdx.x & 63, w = threadIdx.x >> 6;
  int j = blockIdx.x * 64 + lane;       // 16 blocks x 64
  int b0 = w * 4;                       // 8 waves x 4 b
  bool isC = blockIdx.y != 0;
  const float* W = isC ? Wc : Wh;
  const float* bias = isC ? bc : bh;
  float* dst = isC ? cT0 : hT0;
  const float* wrow = W + (size_t)j * 512;
  float acc[4] = {0.f, 0.f, 0.f, 0.f};
  for (int k = 0; k < 512; k += 4) {
    float4 wv = *(const float4*)(wrow + k);
#pragma unroll
    for (int kk = 0; kk < 4; ++kk) {
      float a = (kk == 0) ? wv.x : (kk == 1) ? wv.y : (kk == 2) ? wv.z : wv.w;
#pragma unroll
      for (int bb = 0; bb < 4; ++bb)
        acc[bb] += a * cond[(size_t)(b0 + bb) * 512 + k + kk];
    }
  }
  float bj = bias[j];
#pragma unroll
  for (int bb = 0; bb < 4; ++bb) dst[j * 32 + b0 + bb] = acc[bb] + bj;
}

// ---------------- K0b: eT <- embed[START], xhist[0][:]=1 ---------------------
__global__ __launch_bounds__(256) void k_init2(const float* __restrict__ embed,
                                               float* __restrict__ eT, int* __restrict__ xhist) {
  int flat = blockIdx.x * 256 + threadIdx.x;    // 64 blocks -> 16384
  int k = flat >> 5;
  eT[flat] = embed[512 + k];                    // token 1 row, same for every b
  if (flat < 32) xhist[flat] = 1;
}

// ---------------- KG: gates GEMM + LSTM pointwise + prev-store --------------
__global__ __launch_bounds__(512) void k_gates(
    const float* __restrict__ Wih, const float* __restrict__ Whh,
    const float* __restrict__ bih, const float* __restrict__ bhh,
    const float* __restrict__ eT, const float* __restrict__ hT_cur,
    const float* __restrict__ cT_cur,
    float* __restrict__ hT_nxt, float* __restrict__ cT_nxt,
    float* __restrict__ hprev_dst, float* __restrict__ cprev_dst, int direct) {
  int bxx = blockIdx.x;                 // 128 = 64 ht-tiles x 2 b-halves
  int ht = bxx >> 1, b0 = (bxx & 1) * 16;
  int tid = threadIdx.x, w = tid >> 6, lane = tid & 63;
  int gate = lane >> 4, hh = lane & 15;
  int j = gate * 1024 + ht * 16 + hh;
  float acc[16];
#pragma unroll
  for (int q = 0; q < 16; ++q) acc[q] = 0.f;
  {   // e-part: wave w covers k in [w*64, w*64+64)
    const float* wrow = Wih + (size_t)j * 512;
    int kb = w * 64;
    for (int k = kb; k < kb + 64; k += 4) {
      float4 wv = *(const float4*)(wrow + k);
#pragma unroll
      for (int kk = 0; kk < 4; ++kk) {
        float a = (kk == 0) ? wv.x : (kk == 1) ? wv.y : (kk == 2) ? wv.z : wv.w;
        const float* er = eT + (k + kk) * 32 + b0;
#pragma unroll
        for (int bq = 0; bq < 4; ++bq) {
          float4 ev = *(const float4*)(er + bq * 4);
          acc[bq*4+0] += a * ev.x; acc[bq*4+1] += a * ev.y;
          acc[bq*4+2] += a * ev.z; acc[bq*4+3] += a * ev.w;
        }
      }
    }
  }
  {   // h-part: wave w covers k in [w*128, w*128+128)
    const float* wrow = Whh + (size_t)j * 1024;
    int kb = w * 128;
    for (int k = kb; k < kb + 128; k += 4) {
      float4 wv = *(const float4*)(wrow + k);
#pragma unroll
      for (int kk = 0; kk < 4; ++kk) {
        float a = (kk == 0) ? wv.x : (kk == 1) ? wv.y : (kk == 2) ? wv.z : wv.w;
        const float* hr = hT_cur + (k + kk) * 32 + b0;
#pragma unroll
        for (int bq = 0; bq < 4; ++bq) {
          float4 hv = *(const float4*)(hr + bq * 4);
          acc[bq*4+0] += a * hv.x; acc[bq*4+1] += a * hv.y;
          acc[bq*4+2] += a * hv.z; acc[bq*4+3] += a * hv.w;
        }
      }
    }
  }
  __shared__ float lds[8][64][16];      // 32 KB
  __shared__ float gsum[64][16];        // 4 KB
#pragma unroll
  for (int q = 0; q < 16; q += 4)
    *(float4*)&lds[w][lane][q] = make_float4(acc[q], acc[q+1], acc[q+2], acc[q+3]);
  __syncthreads();
#pragma unroll
  for (int it = 0; it < 2; ++it) {
    int flat = it * 512 + tid;          // 1024 (gi, bb) pairs
    int gi = flat >> 4, bb = flat & 15;
    float s = 0.f;
#pragma unroll
    for (int ww = 0; ww < 8; ++ww) s += lds[ww][gi][bb];
    int jj = (gi >> 4) * 1024 + ht * 16 + (gi & 15);
    gsum[gi][bb] = s + bih[jj] + bhh[jj];
  }
  __syncthreads();
  if (tid < 256) {
    int hh2 = tid >> 4, bb = tid & 15;
    int hidx = ht * 16 + hh2, b = b0 + bb;
    float iv = gsum[hh2][bb];
    float fv = gsum[16 + hh2][bb];
    float gv = gsum[32 + hh2][bb];
    float ov = gsum[48 + hh2][bb];
    float cold = cT_cur[hidx * 32 + b];
    float hold = hT_cur[hidx * 32 + b];
    float si = 1.f / (1.f + expf(-iv));
    float sf = 1.f / (1.f + expf(-fv));
    float so = 1.f / (1.f + expf(-ov));
    float cn = sf * cold + si * tanhf(gv);
    float hn = so * tanhf(cn);
    cT_nxt[hidx * 32 + b] = cn;
    hT_nxt[hidx * 32 + b] = hn;
    size_t oi = (size_t)(b * 1024 + hidx);
    if (direct) oi *= 48;
    hprev_dst[oi] = hold;
    cprev_dst[oi] = cold;
  }
}

// ---------------- KL: logits GEMM (k-split partials) ------------------------
__global__ __launch_bounds__(64) void k_logits(const float* __restrict__ W,
                                               const float* __restrict__ hT,
                                               float* __restrict__ partials, int ksplit) {
  int bx = blockIdx.x;
  int vt = bx / ksplit, kc = bx - vt * ksplit;
  int lane = threadIdx.x;
  int v = vt * 128 + lane;              // this lane covers v and v+64
  const float* w0 = W + (size_t)v * 1024;
  const float* w1 = w0 + (size_t)64 * 1024;
  float acc0[32], acc1[32];
#pragma unroll
  for (int b = 0; b < 32; ++b) { acc0[b] = 0.f; acc1[b] = 0.f; }
  int kn = 1024 / ksplit;
  int kbeg = kc * kn, kend = kbeg + kn;
  // 2-deep manual pipeline on the lane-private W row streams
  float4 wa = *(const float4*)(w0 + kbeg);
  float4 wb = *(const float4*)(w1 + kbeg);
  for (int k = kbeg; k < kend; k += 4) {
    float4 na, nb;
    if (k + 4 < kend) {
      na = *(const float4*)(w0 + k + 4);
      nb = *(const float4*)(w1 + k + 4);
    }
    const float* hr = hT + k * 32;
#pragma unroll
    for (int kk = 0; kk < 4; ++kk) {
      float a = (kk == 0) ? wa.x : (kk == 1) ? wa.y : (kk == 2) ? wa.z : wa.w;
      float c = (kk == 0) ? wb.x : (kk == 1) ? wb.y : (kk == 2) ? wb.z : wb.w;
      const float* hk = hr + kk * 32;
#pragma unroll
      for (int bq = 0; bq < 8; ++bq) {
        float4 hv = *(const float4*)(hk + bq * 4);
        acc0[bq*4+0] += a * hv.x; acc0[bq*4+1] += a * hv.y;
        acc0[bq*4+2] += a * hv.z; acc0[bq*4+3] += a * hv.w;
        acc1[bq*4+0] += c * hv.x; acc1[bq*4+1] += c * hv.y;
        acc1[bq*4+2] += c * hv.z; acc1[bq*4+3] += c * hv.w;
      }
    }
    wa = na; wb = nb;
  }
  size_t pb = (size_t)kc * 1024000 + v;
#pragma unroll
  for (int b = 0; b < 32; ++b) {
    partials[pb + (size_t)b * 32000] = acc0[b];
    partials[pb + (size_t)b * 32000 + 64] = acc1[b];
  }
}

// ---------------- KZ: per-chunk reduce+bias, gumbel, partial softmax --------
// grid (NCHUNK, B), 1024 threads. Writes l into lbuf; per-chunk records:
// cr_m (chunk max), cr_s (sum exp(l-m_c)), cr_z/cr_zi (gumbel argmax).
// PRNG: JAX threefry_partitionable semantics (default True in modern JAX):
//   bits[j] = o0 ^ o1 of threefry2x32(step_key, (0, j)), j = b*32000 + v.
__global__ __launch_bounds__(1024) void k_znoise(
    const float* __restrict__ partials, int ksplit,
    const float* __restrict__ blog,
    float* __restrict__ lbuf,
    float* __restrict__ cr_m, float* __restrict__ cr_s,
    float* __restrict__ cr_z, int* __restrict__ cr_zi,
    unsigned int k0, unsigned int k1) {
  int c = blockIdx.x, b = blockIdx.y;
  int tid = threadIdx.x, lane = tid & 63, wid = tid >> 6;
  int vbase = c * CHV;
  float lv[4];
  int n = 0;
  float lmax = -3.402823466e38f, bz = -3.402823466e38f;
  int bi = 0x7FFFFFFF;
#pragma unroll
  for (int i = 0; i < 4; ++i) {
    int v = vbase + tid + i * 1024;
    if (v < vbase + CHV) {
      float l = blog[v];
      for (int kc = 0; kc < ksplit; ++kc)
        l += partials[(size_t)kc * 1024000 + (size_t)b * 32000 + v];
      lbuf[(size_t)b * 32000 + v] = l;
      lv[n] = l; ++n;
      lmax = fmaxf(lmax, l);
      unsigned int j = (unsigned int)(b * 32000 + v);
      unsigned int r0, r1;
      threefry2x32(k0, k1, 0u, j, r0, r1);
      unsigned int bits = r0 ^ r1;
      float f = __uint_as_float((bits >> 9) | 0x3f800000u) - 1.0f;
      f = fmaxf(f, 1.1754943508222875e-38f);
      float g = -logf(-logf(f));
      float z = l + g;
      if (z > bz) { bz = z; bi = v; }   // strict >: first index wins (v asc)
    }
  }
  __shared__ float sm[16], ss[16], sz[16];
  __shared__ int szi[16];
  __shared__ float s_mc;
  // chunk max
#pragma unroll
  for (int off = 32; off > 0; off >>= 1) lmax = fmaxf(lmax, __shfl_down(lmax, off));
  if (lane == 0) sm[wid] = lmax;
  __syncthreads();
  if (tid == 0) {
    float m2 = sm[0];
    for (int w2 = 1; w2 < 16; ++w2) m2 = fmaxf(m2, sm[w2]);
    s_mc = m2;
  }
  __syncthreads();
  float mc = s_mc;
  // chunk partial sum of exp(l - mc)
  float s = 0.f;
  for (int i = 0; i < n; ++i) s += expf(lv[i] - mc);
#pragma unroll
  for (int off = 32; off > 0; off >>= 1) s += __shfl_down(s, off);
  // chunk gumbel argmax
#pragma unroll
  for (int off = 32; off > 0; off >>= 1) {
    float oz = __shfl_down(bz, off); int oi = __shfl_down(bi, off);
    if (oz > bz || (oz == bz && oi < bi)) { bz = oz; bi = oi; }
  }
  if (lane == 0) { ss[wid] = s; sz[wid] = bz; szi[wid] = bi; }
  __syncthreads();
  if (tid == 0) {
    float S = 0.f;
    for (int w2 = 0; w2 < 16; ++w2) S += ss[w2];
    float Z = sz[0]; int I = szi[0];
    for (int w2 = 1; w2 < 16; ++w2) {
      if (sz[w2] > Z || (sz[w2] == Z && szi[w2] < I)) { Z = sz[w2]; I = szi[w2]; }
    }
    int rec = b * NCHUNK + c;
    cr_m[rec] = mc; cr_s[rec] = S; cr_z[rec] = Z; cr_zi[rec] = I;
  }
}

// ---------------- KP: logp write + (block x==0) token finalize + eT gather --
// grid (32, B), 1024 threads; each x-block covers 1000 v.
__global__ __launch_bounds__(1024) void k_logp(
    const float* lbuf_in,
    const float* __restrict__ cr_m, const float* __restrict__ cr_s,
    const float* __restrict__ cr_z, const int* __restrict__ cr_zi,
    float* logp_dst, int direct,
    const float* __restrict__ embed, float* __restrict__ eT,
    float* __restrict__ cap, int* __restrict__ xhist, int t) {
  int bx = blockIdx.x, b = blockIdx.y, tid = threadIdx.x;
  // deterministic LSE from the 8 chunk records (fixed order)
  float M = -3.402823466e38f;
#pragma unroll
  for (int c = 0; c < NCHUNK; ++c) M = fmaxf(M, cr_m[b * NCHUNK + c]);
  float S = 0.f;
#pragma unroll
  for (int c = 0; c < NCHUNK; ++c) S += cr_s[b * NCHUNK + c] * expf(cr_m[b * NCHUNK + c] - M);
  float LSE = M + logf(S);
  int v = bx * 1000 + tid;
  if (tid < 1000) {
    float lp = lbuf_in[(size_t)b * 32000 + v] - LSE;
    if (direct) logp_dst[(size_t)(b * 32000 + v) * 48] = lp;
    else        logp_dst[(size_t)b * 32000 + v] = lp;
  }
  if (bx == 0) {
    __shared__ int stok;
    if (tid == 0) {
      float Z = -3.402823466e38f; int I = 0x7FFFFFFF;
#pragma unroll
      for (int c = 0; c < NCHUNK; ++c) {
        float z = cr_z[b * NCHUNK + c]; int i2 = cr_zi[b * NCHUNK + c];
        if (z > Z || (z == Z && i2 < I)) { Z = z; I = i2; }
      }
      stok = I;
      xhist[(t + 1) * 32 + b] = I;
      cap[b * 48 + t] = (float)I;
    }
    __syncthreads();
    int tok = stok;
    for (int k = tid; k < 512; k += 1024) eT[k * 32 + b] = embed[(size_t)tok * 512 + k];
  }
}

// ---------------- KT1: logp [T][B][V] -> out [B][V][T] ----------------------
__global__ __launch_bounds__(256) void k_tr_logp(const float* __restrict__ src,
                                                 float* __restrict__ dst) {
  int vt = blockIdx.x, b = blockIdx.y;          // (500, 32)
  __shared__ float lds[48][65];
#pragma unroll
  for (int it = 0; it < 12; ++it) {
    int flat = it * 256 + threadIdx.x;
    int tt = flat >> 6, vv = flat & 63;
    lds[tt][vv] = src[(size_t)tt * 1024000 + (size_t)b * 32000 + vt * 64 + vv];
  }
  __syncthreads();
#pragma unroll
  for (int it = 0; it < 12; ++it) {
    int flat = it * 256 + threadIdx.x;
    int vv = flat / 48, tt = flat - vv * 48;
    dst[((size_t)(b * 32000 + vt * 64 + vv)) * 48 + tt] = lds[tt][vv];
  }
}

// ---------------- KT2: h/c [T][B][H] -> out [B][H][T] -----------------------
__global__ __launch_bounds__(256) void k_tr_hc(const float* __restrict__ hbuf,
                                               const float* __restrict__ cbuf,
                                               float* __restrict__ out) {
  int jt = blockIdx.x, b = blockIdx.y, z = blockIdx.z;  // (16, 32, 2)
  const float* src = z ? cbuf : hbuf;
  float* dst = out + (z ? (size_t)OUT_C : (size_t)OUT_H);
  __shared__ float lds[48][65];
#pragma unroll
  for (int it = 0; it < 12; ++it) {
    int flat = it * 256 + threadIdx.x;
    int tt = flat >> 6, jj = flat & 63;
    lds[tt][jj] = src[(size_t)tt * 32768 + (size_t)b * 1024 + jt * 64 + jj];
  }
  __syncthreads();
#pragma unroll
  for (int it = 0; it < 12; ++it) {
    int flat = it * 256 + threadIdx.x;
    int jj = flat / 48, tt = flat - jj * 48;
    dst[((size_t)(b * 1024 + jt * 64 + jj)) * 48 + tt] = lds[tt][jj];
  }
}

// ---------------- host ------------------------------------------------------
extern "C" void kernel_launch(void* const* d_in, const int* in_sizes, int n_in,
                              void* d_out, int out_size, void* d_ws, size_t ws_size,
                              hipStream_t stream) {
  const float* cond  = (const float*)d_in[0];
  const float* Wh    = (const float*)d_in[1];
  const float* bh    = (const float*)d_in[2];
  const float* Wc    = (const float*)d_in[3];
  const float* bc    = (const float*)d_in[4];
  const float* embed = (const float*)d_in[5];
  const float* Wih   = (const float*)d_in[6];
  const float* Whh   = (const float*)d_in[7];
  const float* bih   = (const float*)d_in[8];
  const float* bhh   = (const float*)d_in[9];
  const float* Wlog  = (const float*)d_in[10];
  const float* blog  = (const float*)d_in[11];
  float* out = (float*)d_out;

  float* wsf = (float*)d_ws;
  int*   xhist = (int*)d_ws;                    // 2048 floats reserved
  float* hT0 = wsf + 2048;
  float* hT1 = hT0 + 32768;
  float* cT0 = hT1 + 32768;
  float* cT1 = cT0 + 32768;
  float* eT  = cT1 + 32768;                     // 16384
  float* cr_m = eT + 16384;                     // 256
  float* cr_s = cr_m + 256;                     // 256
  float* cr_z = cr_s + 256;                     // 256
  int*   cr_zi = (int*)(cr_z + 256);            // 256
  float* logits = cr_z + 512;                   // 1,024,000 scratch (direct mode)
  float* partials = logits + 1024000;           // ksplit * 1,024,000

  size_t fixed = 2048 + 4 * 32768 + 16384 + 1024 + 1024000;
  size_t base8 = fixed + (size_t)8 * 1024000;
  int ksplit = (ws_size >= base8 * 4) ? 8 : 1;
  size_t base = fixed + (size_t)ksplit * 1024000;
  size_t buf_extra = (size_t)T_MAX * B * V + 2ull * T_MAX * B * H;
  bool buffered = ws_size >= (base + buf_extra) * 4;
  float* logpbuf = partials + (size_t)ksplit * 1024000;
  float* hbuf = logpbuf + (size_t)T_MAX * B * V;
  float* cbuf = hbuf + (size_t)T_MAX * B * H;

  // step keys: jax.random.split(jax.random.key(42), 48) under
  // jax_threefry_partitionable=True (modern default): fold-like split,
  // key[t] = threefry2x32((0,42), (0, t)) giving the full (o0, o1) pair.
  unsigned int ka[48], kb[48];
  for (int i = 0; i < 48; ++i) {
    unsigned int a, c;
    threefry2x32(0u, 42u, 0u, (unsigned int)i, a, c);
    ka[i] = a; kb[i] = c;
  }

  k_init<<<dim3(16, 2), dim3(512), 0, stream>>>(cond, Wh, bh, Wc, bc, hT0, cT0);
  k_init2<<<dim3(64), dim3(256), 0, stream>>>(embed, eT, xhist);

  float* hTs[2] = {hT0, hT1};
  float* cTs[2] = {cT0, cT1};
  for (int t = 0; t < T_MAX; ++t) {
    int cur = t & 1, nxt = cur ^ 1;
    float* hpd = buffered ? (hbuf + (size_t)t * 32768) : (out + OUT_H + t);
    float* cpd = buffered ? (cbuf + (size_t)t * 32768) : (out + OUT_C + t);
    k_gates<<<dim3(128), dim3(512), 0, stream>>>(
        Wih, Whh, bih, bhh, eT, hTs[cur], cTs[cur], hTs[nxt], cTs[nxt],
        hpd, cpd, buffered ? 0 : 1);
    k_logits<<<dim3(250 * ksplit), dim3(64), 0, stream>>>(Wlog, hTs[nxt], partials, ksplit);
    float* lbuf = buffered ? (logpbuf + (size_t)t * 1024000) : logits;
    k_znoise<<<dim3(NCHUNK, B), dim3(1024), 0, stream>>>(
        partials, ksplit, blog, lbuf, cr_m, cr_s, cr_z, cr_zi,
        ka[t], kb[t]);
    float* lpd = buffered ? lbuf : (out + OUT_LOGP + t);
    k_logp<<<dim3(32, B), dim3(1024), 0, stream>>>(
        lbuf, cr_m, cr_s, cr_z, cr_zi, lpd, buffered ? 0 : 1,
        embed, eT, out, xhist, t);
  }
  if (buffered) {
    k_tr_logp<<<dim3(500, 32), dim3(256), 0, stream>>>(logpbuf, out + OUT_LOGP);
    k_tr_hc<<<dim3(16, 32, 2), dim3(256), 0, stream>>>(hbuf, cbuf, out);
  }
}